// Round 3
// baseline (1441.208 us; speedup 1.0000x reference)
//
#include <hip/hip_runtime.h>

// GaussianSoftmax: out[b,n,m] = softmax_m( exp( exp(-max(||x_n-x_m||^2,0)/sigma) ) )
// X: [8, 4096, 16] fp32, sigma: [1], out: [8, 4096, 4096] fp32 (512 MiB).
// R2: (a) pack X -> Xt[b][f][m] in d_ws so inner-loop loads are contiguous
// 1KB/instr (fixes 64B-stride sector fragmentation, the R1 bottleneck);
// (b) outer-product register tile: TN=4 rows x 4 consecutive cols/thread,
// e kept in 32 VGPRs (no 64KiB LDS), queries in SGPRs via readfirstlane;
// (c) coalesced float4 stores, output written exactly once.

constexpr int Bn   = 8;
constexpr int N    = 4096;
constexpr int F    = 16;
constexpr int TN   = 4;                 // output rows per block
constexpr int BLK  = 512;               // threads per block (8 waves)
constexpr int ITERS = N / (BLK * 4);    // 2: float4-columns per thread
constexpr int WPB  = BLK / 64;

__global__ __launch_bounds__(256)
void pack_kernel(const float* __restrict__ X, float* __restrict__ Xt) {
    const int b = blockIdx.y;
    const int m = blockIdx.x * 256 + threadIdx.x;
    const float4* src = (const float4*)(X + ((size_t)b * N + m) * F);
    const float4 v0 = src[0], v1 = src[1], v2 = src[2], v3 = src[3];
    const float x[F] = {v0.x, v0.y, v0.z, v0.w, v1.x, v1.y, v1.z, v1.w,
                        v2.x, v2.y, v2.z, v2.w, v3.x, v3.y, v3.z, v3.w};
    float* dst = Xt + (size_t)b * F * N + m;
    #pragma unroll
    for (int f = 0; f < F; ++f) dst[(size_t)f * N] = x[f];   // coalesced dwords
}

__device__ __forceinline__ float uni(float x) {  // force SGPR residency
    return __int_as_float(__builtin_amdgcn_readfirstlane(__float_as_int(x)));
}

__device__ __forceinline__ float gse(float d, float base, float nis) {
    float sqd = fmaxf(fmaf(-2.0f, d, base), 0.0f);
    return __expf(__expf(sqd * nis));
}

__global__ __launch_bounds__(BLK, 4)
void gs_main(const float* __restrict__ X, const float* __restrict__ Xt,
             const float* __restrict__ sigma_p, float* __restrict__ out) {
    __shared__ float red[TN][WPB];

    const int tid = threadIdx.x;
    const int b   = blockIdx.y;
    const int n0  = blockIdx.x * TN;
    const float* Xb = X + (size_t)b * N * F;

    // Query rows: uniform -> SGPRs
    float q[TN][F];
    float sqn[TN];
    #pragma unroll
    for (int r = 0; r < TN; ++r) {
        float s = 0.f;
        #pragma unroll
        for (int f = 0; f < F; ++f) {
            float qq = uni(Xb[(size_t)(n0 + r) * F + f]);
            q[r][f] = qq;
            s = fmaf(qq, qq, s);
        }
        sqn[r] = s;
    }
    const float nis = -1.0f / uni(sigma_p[0]);

    const float4* Xt4 = (const float4*)(Xt + (size_t)b * F * N);

    float4 e4[TN][ITERS];
    float  sum[TN] = {0.f, 0.f, 0.f, 0.f};

    #pragma unroll
    for (int it = 0; it < ITERS; ++it) {
        const int c4 = it * BLK + tid;   // float4 index within the row

        float4 d[TN];
        #pragma unroll
        for (int r = 0; r < TN; ++r) d[r] = make_float4(0.f, 0.f, 0.f, 0.f);
        float4 sq = make_float4(0.f, 0.f, 0.f, 0.f);

        #pragma unroll
        for (int f = 0; f < F; ++f) {
            const float4 v = Xt4[(size_t)f * (N / 4) + c4];  // 1KB/instr contiguous
            sq.x = fmaf(v.x, v.x, sq.x);
            sq.y = fmaf(v.y, v.y, sq.y);
            sq.z = fmaf(v.z, v.z, sq.z);
            sq.w = fmaf(v.w, v.w, sq.w);
            #pragma unroll
            for (int r = 0; r < TN; ++r) {
                d[r].x = fmaf(q[r][f], v.x, d[r].x);
                d[r].y = fmaf(q[r][f], v.y, d[r].y);
                d[r].z = fmaf(q[r][f], v.z, d[r].z);
                d[r].w = fmaf(q[r][f], v.w, d[r].w);
            }
        }

        #pragma unroll
        for (int r = 0; r < TN; ++r) {
            float4 e;
            e.x = gse(d[r].x, sqn[r] + sq.x, nis);
            e.y = gse(d[r].y, sqn[r] + sq.y, nis);
            e.z = gse(d[r].z, sqn[r] + sq.z, nis);
            e.w = gse(d[r].w, sqn[r] + sq.w, nis);
            e4[r][it] = e;
            sum[r] += (e.x + e.y) + (e.z + e.w);
        }
    }

    // Softmax denominator: wave shuffle reduce, then cross-wave via LDS.
    #pragma unroll
    for (int r = 0; r < TN; ++r) {
        float s = sum[r];
        #pragma unroll
        for (int off = 32; off > 0; off >>= 1) s += __shfl_down(s, off, 64);
        if ((tid & 63) == 0) red[r][tid >> 6] = s;
    }
    __syncthreads();

    float inv[TN];
    #pragma unroll
    for (int r = 0; r < TN; ++r) {
        float t = 0.f;
        #pragma unroll
        for (int w = 0; w < WPB; ++w) t += red[r][w];
        inv[r] = 1.0f / t;
    }

    // Coalesced float4 stores; output written exactly once.
    float* outb = out + ((size_t)b * N + n0) * (size_t)N;
    #pragma unroll
    for (int r = 0; r < TN; ++r) {
        #pragma unroll
        for (int it = 0; it < ITERS; ++it) {
            float4 v = e4[r][it];
            v.x *= inv[r]; v.y *= inv[r]; v.z *= inv[r]; v.w *= inv[r];
            ((float4*)(outb + (size_t)r * N))[it * BLK + tid] = v;
        }
    }
}

extern "C" void kernel_launch(void* const* d_in, const int* in_sizes, int n_in,
                              void* d_out, int out_size, void* d_ws, size_t ws_size,
                              hipStream_t stream) {
    const float* X     = (const float*)d_in[0];
    const float* sigma = (const float*)d_in[1];
    float* out         = (float*)d_out;
    float* Xt          = (float*)d_ws;   // 8*16*4096*4 B = 2 MiB

    pack_kernel<<<dim3(N / 256, Bn), 256, 0, stream>>>(X, Xt);
    gs_main<<<dim3(N / TN, Bn), BLK, 0, stream>>>(X, Xt, sigma, out);
}

// Round 4
// 589.190 us; speedup vs baseline: 2.4461x; 2.4461x over previous
//
#include <hip/hip_runtime.h>

// GaussianSoftmax: out[b,n,m] = softmax_m( exp( exp(-max(||x_n-x_m||^2,0)/sigma) ) )
// X: [8, 4096, 16] fp32, sigma: [1], out: [8, 4096, 4096] fp32 (512 MiB).
// R4 = R1 structure (e in 64KiB LDS -> no big register arrays, output written
// exactly once, coalesced) + R2's packed Xt[b][f][m] loads (1KB/wave contiguous,
// no sector fragmentation). R3's spill (q+e4 arrays under a 128-VGPR cap) is
// avoided by keeping e in LDS; live state ~110 VGPR fits 4 waves/SIMD.

constexpr int Bn  = 8;
constexpr int N   = 4096;
constexpr int F   = 16;
constexpr int TN  = 4;     // output rows per block
constexpr int BLK = 512;   // 8 waves; LDS-bound 2 blocks/CU = 4 waves/SIMD
constexpr int WPB = BLK / 64;
constexpr int ITERS = N / (BLK * 4);   // 2 float4-column groups per thread

__global__ __launch_bounds__(256)
void pack_kernel(const float* __restrict__ X, float* __restrict__ Xt) {
    const int b = blockIdx.y;
    const int m = blockIdx.x * 256 + threadIdx.x;
    const float4* src = (const float4*)(X + ((size_t)b * N + m) * F);
    const float4 v0 = src[0], v1 = src[1], v2 = src[2], v3 = src[3];
    const float x[F] = {v0.x, v0.y, v0.z, v0.w, v1.x, v1.y, v1.z, v1.w,
                        v2.x, v2.y, v2.z, v2.w, v3.x, v3.y, v3.z, v3.w};
    float* dst = Xt + (size_t)b * F * N + m;
    #pragma unroll
    for (int f = 0; f < F; ++f) dst[(size_t)f * N] = x[f];   // coalesced dwords
}

__device__ __forceinline__ float dot4(float4 a, float4 b) {
    return fmaf(a.x, b.x, fmaf(a.y, b.y, fmaf(a.z, b.z, a.w * b.w)));
}

__device__ __forceinline__ float gse(float d, float base, float nis) {
    float sqd = fmaxf(fmaf(-2.0f, d, base), 0.0f);
    return __expf(__expf(sqd * nis));
}

__global__ __launch_bounds__(BLK, 4)
void gs_main(const float* __restrict__ X, const float* __restrict__ Xt,
             const float* __restrict__ sigma_p, float* __restrict__ out) {
    __shared__ float lds_e[TN][N];        // 64 KiB
    __shared__ float red[TN][WPB];

    const int tid = threadIdx.x;
    const int b   = blockIdx.y;
    const int n0  = blockIdx.x * TN;
    const float* Xb = X + (size_t)b * N * F;

    // Query rows: thread-uniform float4 loads -> scalar regs (R1-proven, no spill).
    float4 q0[TN], q1[TN], q2[TN], q3[TN];
    float  sqn[TN];
    #pragma unroll
    for (int r = 0; r < TN; ++r) {
        const float4* qp = (const float4*)(Xb + (size_t)(n0 + r) * F);
        q0[r] = qp[0]; q1[r] = qp[1]; q2[r] = qp[2]; q3[r] = qp[3];
        sqn[r] = dot4(q0[r], q0[r]) + dot4(q1[r], q1[r])
               + dot4(q2[r], q2[r]) + dot4(q3[r], q3[r]);
    }
    const float nis = -1.0f / sigma_p[0];

    const float4* Xt4 = (const float4*)(Xt + (size_t)b * F * N);

    float sum[TN] = {0.f, 0.f, 0.f, 0.f};

    #pragma unroll
    for (int it = 0; it < ITERS; ++it) {
        const int c4 = it * BLK + tid;   // float4-column index

        float4 d[TN];
        #pragma unroll
        for (int r = 0; r < TN; ++r) d[r] = make_float4(0.f, 0.f, 0.f, 0.f);
        float4 sq = make_float4(0.f, 0.f, 0.f, 0.f);

        // f-major: each load is 1KB/wave contiguous (16 independent loads -> ILP)
        #pragma unroll
        for (int f4 = 0; f4 < F / 4; ++f4) {
            float4 v[4];
            #pragma unroll
            for (int j = 0; j < 4; ++j)
                v[j] = Xt4[(size_t)(f4 * 4 + j) * (N / 4) + c4];
            #pragma unroll
            for (int j = 0; j < 4; ++j) {
                const float4 w = v[j];
                sq.x = fmaf(w.x, w.x, sq.x);
                sq.y = fmaf(w.y, w.y, sq.y);
                sq.z = fmaf(w.z, w.z, sq.z);
                sq.w = fmaf(w.w, w.w, sq.w);
                #pragma unroll
                for (int r = 0; r < TN; ++r) {
                    const float4 qr = (f4 == 0) ? ((j == 0) ? q0[r] : (j == 1) ? q1[r] : (j == 2) ? q2[r] : q3[r])
                                                : ((j == 0) ? q0[r] : (j == 1) ? q1[r] : (j == 2) ? q2[r] : q3[r]);
                    // scalar q element for this f = component j of q-block f4
                    float qf = (f4 == 0) ? 0.f : 0.f;  // placeholder, replaced below
                    (void)qr; (void)qf;
                }
            }
        }

        // ---- The above exploratory form replaced by a direct formulation ----
        // (kept simple and allocator-friendly): recompute with explicit blocks.
        #pragma unroll
        for (int r = 0; r < TN; ++r) d[r] = make_float4(0.f, 0.f, 0.f, 0.f);
        sq = make_float4(0.f, 0.f, 0.f, 0.f);

        #pragma unroll
        for (int fb = 0; fb < 4; ++fb) {        // f-block of 4 features
            float4 v0 = Xt4[(size_t)(fb * 4 + 0) * (N / 4) + c4];
            float4 v1 = Xt4[(size_t)(fb * 4 + 1) * (N / 4) + c4];
            float4 v2 = Xt4[(size_t)(fb * 4 + 2) * (N / 4) + c4];
            float4 v3 = Xt4[(size_t)(fb * 4 + 3) * (N / 4) + c4];

            #pragma unroll
            for (int k = 0; k < 4; ++k) {
                const float4 w = (k == 0) ? v0 : (k == 1) ? v1 : (k == 2) ? v2 : v3;
                sq.x = fmaf(w.x, w.x, sq.x);
                sq.y = fmaf(w.y, w.y, sq.y);
                sq.z = fmaf(w.z, w.z, sq.z);
                sq.w = fmaf(w.w, w.w, sq.w);
                #pragma unroll
                for (int r = 0; r < TN; ++r) {
                    const float4 qb = (fb == 0) ? q0[r] : (fb == 1) ? q1[r]
                                    : (fb == 2) ? q2[r] : q3[r];
                    const float qf = (k == 0) ? qb.x : (k == 1) ? qb.y
                                   : (k == 2) ? qb.z : qb.w;
                    d[r].x = fmaf(qf, w.x, d[r].x);
                    d[r].y = fmaf(qf, w.y, d[r].y);
                    d[r].z = fmaf(qf, w.z, d[r].z);
                    d[r].w = fmaf(qf, w.w, d[r].w);
                }
            }
        }

        #pragma unroll
        for (int r = 0; r < TN; ++r) {
            float4 e;
            e.x = gse(d[r].x, sqn[r] + sq.x, nis);
            e.y = gse(d[r].y, sqn[r] + sq.y, nis);
            e.z = gse(d[r].z, sqn[r] + sq.z, nis);
            e.w = gse(d[r].w, sqn[r] + sq.w, nis);
            ((float4*)lds_e[r])[c4] = e;          // ds_write_b128, conflict-free
            sum[r] += (e.x + e.y) + (e.z + e.w);
        }
    }

    // Softmax denominator: wave shuffle reduce, then cross-wave via LDS.
    #pragma unroll
    for (int r = 0; r < TN; ++r) {
        float s = sum[r];
        #pragma unroll
        for (int off = 32; off > 0; off >>= 1) s += __shfl_down(s, off, 64);
        if ((tid & 63) == 0) red[r][tid >> 6] = s;
    }
    __syncthreads();

    float inv[TN];
    #pragma unroll
    for (int r = 0; r < TN; ++r) {
        float t = 0.f;
        #pragma unroll
        for (int w = 0; w < WPB; ++w) t += red[r][w];
        inv[r] = 1.0f / t;
    }

    // Coalesced float4 stores; output written exactly once.
    float* outb = out + ((size_t)b * N + n0) * (size_t)N;
    #pragma unroll
    for (int r = 0; r < TN; ++r) {
        #pragma unroll
        for (int it = 0; it < ITERS; ++it) {
            const int c4 = it * BLK + tid;
            float4 v = ((const float4*)lds_e[r])[c4];
            v.x *= inv[r]; v.y *= inv[r]; v.z *= inv[r]; v.w *= inv[r];
            ((float4*)(outb + (size_t)r * N))[c4] = v;
        }
    }
}

extern "C" void kernel_launch(void* const* d_in, const int* in_sizes, int n_in,
                              void* d_out, int out_size, void* d_ws, size_t ws_size,
                              hipStream_t stream) {
    const float* X     = (const float*)d_in[0];
    const float* sigma = (const float*)d_in[1];
    float* out         = (float*)d_out;
    float* Xt          = (float*)d_ws;   // 2 MiB

    pack_kernel<<<dim3(N / 256, Bn), 256, 0, stream>>>(X, Xt);
    gs_main<<<dim3(N / TN, Bn), BLK, 0, stream>>>(X, Xt, sigma, out);
}